// Round 3
// baseline (145.771 us; speedup 1.0000x reference)
//
#include <hip/hip_runtime.h>

// Pointer-generator final distribution, 3-kernel split.
//   k1 gate:    p_gen[b] = sigmoid(ctx.w_c + state.w_s + emb.w_y + bias) -> d_ws
//   k2 scale:   out[b,v] = p_gen[b] * vocab_dist[b,v]   (1 float4/thread, streaming)
//   k3 scatter: out[b, src_ids[b,t]] += (1-p_gen[b]) * attn[b,t]  (atomics)
// Stream order carries k1->k2->k3 dependencies (dispatch-boundary coherence).
// R0/R1 single-kernel versions plateaued at ~39-41 us (phase barriers +
// 512-block grid starved the memory pipe); copy roofline for k2 is ~21 us.

__global__ __launch_bounds__(256) void pg_gate_kernel(
    const float* __restrict__ context,  // [B,ENC]
    const float* __restrict__ state,    // [B,HID]
    const float* __restrict__ emb,      // [B,EMB]
    const float* __restrict__ w_c, const float* __restrict__ w_s,
    const float* __restrict__ w_y, const float* __restrict__ bias,
    float* __restrict__ pg,             // [B] out
    int ENC, int HID, int EMB)
{
    const int row = blockIdx.x;
    const int tid = threadIdx.x;
    float acc = 0.f;
    {
        const float4* a4 = (const float4*)(context + (size_t)row * ENC);
        const float4* w4 = (const float4*)w_c;
        for (int i = tid; i < (ENC >> 2); i += 256) {
            float4 a = a4[i], w = w4[i];
            acc += a.x * w.x + a.y * w.y + a.z * w.z + a.w * w.w;
        }
    }
    {
        const float4* a4 = (const float4*)(state + (size_t)row * HID);
        const float4* w4 = (const float4*)w_s;
        for (int i = tid; i < (HID >> 2); i += 256) {
            float4 a = a4[i], w = w4[i];
            acc += a.x * w.x + a.y * w.y + a.z * w.z + a.w * w.w;
        }
    }
    {
        const float4* a4 = (const float4*)(emb + (size_t)row * EMB);
        const float4* w4 = (const float4*)w_y;
        for (int i = tid; i < (EMB >> 2); i += 256) {
            float4 a = a4[i], w = w4[i];
            acc += a.x * w.x + a.y * w.y + a.z * w.z + a.w * w.w;
        }
    }
    #pragma unroll
    for (int off = 32; off > 0; off >>= 1)
        acc += __shfl_down(acc, off, 64);
    __shared__ float red[4];
    if ((tid & 63) == 0) red[tid >> 6] = acc;
    __syncthreads();
    if (tid == 0) {
        float s = red[0] + red[1] + red[2] + red[3] + bias[0];
        pg[row] = 1.f / (1.f + expf(-s));
    }
}

__global__ __launch_bounds__(256) void pg_scale_kernel(
    const float* __restrict__ vocab_dist,  // [B,V]
    const float* __restrict__ pg,          // [B]
    float* __restrict__ out,               // [B,V]
    int V)
{
    const int row = blockIdx.y;               // wave-uniform
    const float p = pg[row];                  // scalar load (uniform)
    const size_t rowV = (size_t)row * V;
    const int nv4 = V >> 2;
    const int i4 = blockIdx.x * 256 + threadIdx.x;
    if (i4 < nv4) {
        float4 v = ((const float4*)(vocab_dist + rowV))[i4];
        v.x *= p; v.y *= p; v.z *= p; v.w *= p;
        ((float4*)(out + rowV))[i4] = v;
    }
    // tail (V % 4): handled here so k3's atomics never race unscaled elems
    const int tail = V & 3;
    if (blockIdx.x == 0 && threadIdx.x < tail) {
        const int idx = (nv4 << 2) + threadIdx.x;
        out[rowV + idx] = vocab_dist[rowV + idx] * p;
    }
}

__global__ __launch_bounds__(256) void pg_scatter_kernel(
    const float* __restrict__ attn_dist,   // [B,T]
    const int*   __restrict__ src_ids,     // [B,T]
    const int*   __restrict__ vocab_size_p,
    const float* __restrict__ pg,          // [B]
    float* __restrict__ out,               // [B,V]
    int T, int V)
{
    const int row = blockIdx.y;
    const int t = blockIdx.x * 256 + threadIdx.x;
    if (t >= T) return;
    const int vs = *vocab_size_p;
    const float pc = 1.f - pg[row];        // uniform scalar load
    const int id = src_ids[(size_t)row * T + t];
    if (id < vs)
        atomicAdd(out + (size_t)row * V + id, pc * attn_dist[(size_t)row * T + t]);
}

extern "C" void kernel_launch(void* const* d_in, const int* in_sizes, int n_in,
                              void* d_out, int out_size, void* d_ws, size_t ws_size,
                              hipStream_t stream) {
    const float* vocab_dist = (const float*)d_in[0];
    const float* attn_dist  = (const float*)d_in[1];
    const float* context    = (const float*)d_in[2];
    const float* state      = (const float*)d_in[3];
    const float* emb        = (const float*)d_in[4];
    const int*   src_ids    = (const int*)d_in[5];
    const int*   vocab_sz   = (const int*)d_in[6];
    const float* w_c        = (const float*)d_in[7];
    const float* w_s        = (const float*)d_in[8];
    const float* w_y        = (const float*)d_in[9];
    const float* bias       = (const float*)d_in[10];
    float* out = (float*)d_out;
    float* pg  = (float*)d_ws;             // [B] floats of scratch

    const int ENC = in_sizes[7];
    const int HID = in_sizes[8];
    const int EMB = in_sizes[9];
    const int B   = in_sizes[2] / ENC;
    const int T   = in_sizes[1] / B;
    const int V   = in_sizes[0] / B;
    const int nv4 = V >> 2;

    pg_gate_kernel<<<B, 256, 0, stream>>>(context, state, emb,
                                          w_c, w_s, w_y, bias, pg,
                                          ENC, HID, EMB);

    dim3 g2((nv4 + 255) / 256, B);
    pg_scale_kernel<<<g2, 256, 0, stream>>>(vocab_dist, pg, out, V);

    dim3 g3((T + 255) / 256, B);
    pg_scatter_kernel<<<g3, 256, 0, stream>>>(attn_dist, src_ids, vocab_sz,
                                              pg, out, T, V);
}

// Round 4
// 139.957 us; speedup vs baseline: 1.0415x; 1.0415x over previous
//
#include <hip/hip_runtime.h>

// Pointer-generator final distribution, 2-kernel version.
//   k1 gate: p_gen[b] = sigmoid(ctx.w_c + state.w_s + emb.w_y + bias) -> d_ws
//   k2 fused scale+scatter, tiled: each block owns an 8192-elem tile of one
//      row. Scatter (1-p)*attn contributions into a 32KB LDS image of the
//      tile (ds_add_f32 — no global atomics), then stream
//      out = p*vocab + lds in one pass. No global RMW, no cross-kernel
//      ordering hazard, one read + one write of the 65.5 MB matrix.
// R2's 3-kernel split (global atomics in a 3rd pass) cost ~44 us device;
// roofline for k2 here is ~21-24 us at the measured 6.6 TB/s ceiling.

#define CHUNK 8192   // floats per tile = 32 KB LDS -> 5 blocks/CU max

__global__ __launch_bounds__(256) void pg_gate_kernel(
    const float* __restrict__ context,  // [B,ENC]
    const float* __restrict__ state,    // [B,HID]
    const float* __restrict__ emb,      // [B,EMB]
    const float* __restrict__ w_c, const float* __restrict__ w_s,
    const float* __restrict__ w_y, const float* __restrict__ bias,
    float* __restrict__ pg,             // [B] out
    int ENC, int HID, int EMB)
{
    const int row = blockIdx.x;
    const int tid = threadIdx.x;
    float acc = 0.f;
    {
        const float4* a4 = (const float4*)(context + (size_t)row * ENC);
        const float4* w4 = (const float4*)w_c;
        for (int i = tid; i < (ENC >> 2); i += 256) {
            float4 a = a4[i], w = w4[i];
            acc += a.x * w.x + a.y * w.y + a.z * w.z + a.w * w.w;
        }
    }
    {
        const float4* a4 = (const float4*)(state + (size_t)row * HID);
        const float4* w4 = (const float4*)w_s;
        for (int i = tid; i < (HID >> 2); i += 256) {
            float4 a = a4[i], w = w4[i];
            acc += a.x * w.x + a.y * w.y + a.z * w.z + a.w * w.w;
        }
    }
    {
        const float4* a4 = (const float4*)(emb + (size_t)row * EMB);
        const float4* w4 = (const float4*)w_y;
        for (int i = tid; i < (EMB >> 2); i += 256) {
            float4 a = a4[i], w = w4[i];
            acc += a.x * w.x + a.y * w.y + a.z * w.z + a.w * w.w;
        }
    }
    #pragma unroll
    for (int off = 32; off > 0; off >>= 1)
        acc += __shfl_down(acc, off, 64);
    __shared__ float red[4];
    if ((tid & 63) == 0) red[tid >> 6] = acc;
    __syncthreads();
    if (tid == 0) {
        float s = red[0] + red[1] + red[2] + red[3] + bias[0];
        pg[row] = 1.f / (1.f + expf(-s));
    }
}

__global__ __launch_bounds__(256) void pg_scale_scatter_kernel(
    const float* __restrict__ vocab_dist,   // [B,V]
    const float* __restrict__ attn_dist,    // [B,T]
    const int*   __restrict__ src_ids,      // [B,T]
    const int*   __restrict__ vocab_size_p, // [1]
    const float* __restrict__ pg,           // [B]
    float* __restrict__ out,                // [B,V]
    int T, int V)
{
    __shared__ float lds[CHUNK];
    const int row = blockIdx.y;
    const int v0  = blockIdx.x * CHUNK;
    const int len = min(CHUNK, V - v0);
    const int tid = threadIdx.x;

    // zero the tile image
    float4* l4 = (float4*)lds;
    #pragma unroll 4
    for (int i = tid; i < (CHUNK >> 2); i += 256)
        l4[i] = make_float4(0.f, 0.f, 0.f, 0.f);

    const float p  = pg[row];               // wave-uniform scalar load
    const float pc = 1.f - p;
    const int   vs = *vocab_size_p;
    __syncthreads();                        // zeros visible before ds_add

    // scatter this row's copy-contributions that land in [v0, v0+len)
    const float* at = attn_dist + (size_t)row * T;
    const int*   si = src_ids  + (size_t)row * T;
    for (int t = tid; t < T; t += 256) {
        int id = si[t];
        if (id < vs) {
            int off = id - v0;
            if ((unsigned)off < (unsigned)len)
                atomicAdd(&lds[off], pc * at[t]);   // ds_add_f32
        }
    }
    __syncthreads();

    // fused stream: out = p * vocab + lds
    const size_t base = (size_t)row * V + v0;
    const float4* vd4 = (const float4*)(vocab_dist + base);
    float4*       o4  = (float4*)(out + base);
    const int n4 = len >> 2;
    for (int i = tid; i < n4; i += 256) {
        float4 v = vd4[i];
        float4 a = l4[i];
        v.x = v.x * p + a.x;
        v.y = v.y * p + a.y;
        v.z = v.z * p + a.z;
        v.w = v.w * p + a.w;
        o4[i] = v;
    }
    for (int i = (n4 << 2) + tid; i < len; i += 256)   // tail (len % 4)
        out[base + i] = vocab_dist[base + i] * p + lds[i];
}

extern "C" void kernel_launch(void* const* d_in, const int* in_sizes, int n_in,
                              void* d_out, int out_size, void* d_ws, size_t ws_size,
                              hipStream_t stream) {
    const float* vocab_dist = (const float*)d_in[0];
    const float* attn_dist  = (const float*)d_in[1];
    const float* context    = (const float*)d_in[2];
    const float* state      = (const float*)d_in[3];
    const float* emb        = (const float*)d_in[4];
    const int*   src_ids    = (const int*)d_in[5];
    const int*   vocab_sz   = (const int*)d_in[6];
    const float* w_c        = (const float*)d_in[7];
    const float* w_s        = (const float*)d_in[8];
    const float* w_y        = (const float*)d_in[9];
    const float* bias       = (const float*)d_in[10];
    float* out = (float*)d_out;
    float* pg  = (float*)d_ws;             // [B] floats of scratch

    const int ENC = in_sizes[7];
    const int HID = in_sizes[8];
    const int EMB = in_sizes[9];
    const int B   = in_sizes[2] / ENC;
    const int T   = in_sizes[1] / B;
    const int V   = in_sizes[0] / B;

    pg_gate_kernel<<<B, 256, 0, stream>>>(context, state, emb,
                                          w_c, w_s, w_y, bias, pg,
                                          ENC, HID, EMB);

    dim3 g2((V + CHUNK - 1) / CHUNK, B);
    pg_scale_scatter_kernel<<<g2, 256, 0, stream>>>(
        vocab_dist, attn_dist, src_ids, vocab_sz, pg, out, T, V);
}